// Round 4
// baseline (220.045 us; speedup 1.0000x reference)
//
#include <hip/hip_runtime.h>

#define DEVFN __device__ __forceinline__

DEVFN float fast_rcp(float x)   { return __builtin_amdgcn_rcpf(x); }
DEVFN float fast_rsqrt(float x) { return __builtin_amdgcn_rsqf(x); }

DEVFN float fast_tanh(float x) {
    // tanh(x) = 1 - 2/(exp(2x)+1); stable at both tails.
    float e = __expf(2.0f * x);
    return 1.0f - 2.0f * fast_rcp(e + 1.0f);
}

DEVFN float fast_asinh(float z) {
    float az = fabsf(z);
    float r = __logf(az + sqrtf(fmaf(az, az, 1.0f)));
    return copysignf(r, z);
}

constexpr int ELEMS = 4;

// ---- per-element physics + MLP ----
DEVFN void battery_compute(
    float4 s0, float4 s1, float i, float qm, float ro, float invTD,
    const float* __restrict__ Wp1, const float* __restrict__ bp1,
    const float* __restrict__ Wp2, const float* __restrict__ bp2,
    const float* __restrict__ Wp3, const float* __restrict__ bp3,
    const float* __restrict__ Wn,  const float* __restrict__ bn,
    float& V, float4& o0, float4& o1)
{
    const float invVOLB = 1.0f / 1.98e-5f;
    const float invVOLS = 1.0f / 2.2e-6f;
    const float RTFA    = 8.3144621f / 96487.0f / 0.5f;  // R/F/alpha
    const float RF      = 8.3144621f / 96487.0f;         // R/F

    const float Tb = s0.x, Vo = s0.y, Vsn = s0.z, Vsp = s0.w;
    const float qnB = s1.x, qnS = s1.y, qpB = s1.z, qpS = s1.w;

    const float qSMax = qm * 1000.0f;
    const float rq    = fast_rcp(qSMax);

    float xpS = fminf(fmaxf(qpS * rq, 1e-18f), 1.0f);
    float xnS = fminf(fmaxf(qnS * rq, 1e-18f), 1.0f);

    // z = i*2500 / (1e-18 + 20000*sqrt(u))  ~=  i*0.125*rsqrt(u)   (u ~ [0.2,0.25])
    float un = (1.0f - xnS) * xnS;
    float up = (1.0f - xpS) * xpS;
    float zn = i * 0.125f * fast_rsqrt(fmaxf(un, 1e-30f));
    float zp = i * 0.125f * fast_rsqrt(fmaxf(up, 1e-30f));

    float qdotn = (qnB * invVOLB - qnS * invVOLS) * invTD;
    float qdotp = (qpB * invVOLB - qpS * invVOLS) * invTD;

    float Vodot = (i * ro * 10.0f - Vo) * 0.1f;

    float VsnNom = RTFA * Tb * fast_asinh(zn);
    float VspNom = RTFA * Tb * fast_asinh(zp);

    const float X0 = Tb;
    const float X1 = Vo + Vodot;
    const float X2 = Vsn + (VsnNom - Vsn) * (1.0f / 90.0f);
    const float X3 = Vsp + (VspNom - Vsp) * (1.0f / 90.0f);
    const float X4 = qnB - qdotn;
    const float X5 = qnS + (qdotn - i);
    const float X6 = qpB - qdotp;
    const float X7 = qpS + (i + qdotp);

    const float xp2 = X7 * rq;
    const float xn2 = X5 * rq;

    // tiny MLP (weights live in scalar regs)
    float h1[8];
#pragma unroll
    for (int j = 0; j < 8; ++j)
        h1[j] = fast_tanh(fmaf(xp2, Wp1[j], bp1[j]));

    float h2[4];
#pragma unroll
    for (int k = 0; k < 4; ++k) {
        float acc = bp2[k];
#pragma unroll
        for (int j = 0; j < 8; ++j)
            acc = fmaf(h1[j], Wp2[j * 4 + k], acc);
        h2[k] = fast_tanh(acc);
    }

    float VepMLP = bp3[0];
#pragma unroll
    for (int k = 0; k < 4; ++k)
        VepMLP = fmaf(h2[k], Wp3[k], VepMLP);

    const float VenMLP = fmaf(xn2, Wn[0], bn[0]);

    // log(slp) - log(sln) = log( (1-xp2)*xn2 / (xp2*(1-xn2)) )
    float ratio = ((1.0f - xp2) * xn2) * fast_rcp(xp2 * (1.0f - xn2));
    float logr  = __logf(ratio);

    V = (4.03f - 0.01f) + RF * X0 * logr + VepMLP - VenMLP - X1 - X2 - X3;
    o0 = make_float4(X0, X1, X2, X3);
    o1 = make_float4(X4, X5, X6, X7);
}

template<bool EXACT>
__global__ __launch_bounds__(256) void battery_step_kernel(
    const float* __restrict__ inputs, const float* __restrict__ states,
    const float* __restrict__ qMax, const float* __restrict__ Ro,
    const float* __restrict__ tDiff,
    const float* __restrict__ Wp1, const float* __restrict__ bp1,
    const float* __restrict__ Wp2, const float* __restrict__ bp2,
    const float* __restrict__ Wp3, const float* __restrict__ bp3,
    const float* __restrict__ Wn,  const float* __restrict__ bn,
    float* __restrict__ outV, float* __restrict__ outX, int n)
{
    const int t      = blockIdx.x * 256 + threadIdx.x;
    const int stride = gridDim.x * 256;

    const float invTD = fast_rcp(tDiff[0]);

    int idx = t;
    float4 s0, s1; float cur, qm, ro;
    bool ok = EXACT || (idx < n);
    if (ok) {
        s0  = ((const float4*)states)[idx * 2 + 0];
        s1  = ((const float4*)states)[idx * 2 + 1];
        cur = inputs[idx];
        qm  = qMax[idx];
        ro  = Ro[idx];
    }

#pragma unroll
    for (int e = 0; e < ELEMS; ++e) {
        float4 ns0, ns1; float ncur, nqm, nro;
        bool nok = false;
        if (e + 1 < ELEMS) {
            int nidx = idx + stride;
            nok = EXACT || (nidx < n);
            if (nok) {
                ns0  = ((const float4*)states)[nidx * 2 + 0];
                ns1  = ((const float4*)states)[nidx * 2 + 1];
                ncur = inputs[nidx];
                nqm  = qMax[nidx];
                nro  = Ro[nidx];
            }
        }

        if (ok) {
            float V; float4 o0, o1;
            battery_compute(s0, s1, cur, qm, ro, invTD,
                            Wp1, bp1, Wp2, bp2, Wp3, bp3, Wn, bn,
                            V, o0, o1);
            outV[idx] = V;
            ((float4*)outX)[idx * 2 + 0] = o0;
            ((float4*)outX)[idx * 2 + 1] = o1;
        }

        idx += stride;
        s0 = ns0; s1 = ns1; cur = ncur; qm = nqm; ro = nro; ok = nok;
    }
}

// ---- ablation B: compute-only (4B/elem in, full chain, 4B/elem out) ----
__global__ __launch_bounds__(256) void ablate_compute_kernel(
    const float* __restrict__ qMax,
    const float* __restrict__ Wp1, const float* __restrict__ bp1,
    const float* __restrict__ Wp2, const float* __restrict__ bp2,
    const float* __restrict__ Wp3, const float* __restrict__ bp3,
    const float* __restrict__ Wn,  const float* __restrict__ bn,
    float* __restrict__ ws)
{
    const int t      = blockIdx.x * 256 + threadIdx.x;
    const int stride = gridDim.x * 256;
#pragma unroll
    for (int e = 0; e < ELEMS; ++e) {
        int idx = t + e * stride;
        float q = qMax[idx];                       // only memory read (4B)
        float b = q * 0.5f + (float)(idx & 1023) * 1e-4f;
        // synthesize plausible state from q
        float4 s0 = make_float4(292.1f + b, 0.01f * b, 0.005f * b, -0.004f * b);
        float4 s1 = make_float4(7560.0f * (1.0f + 0.01f * b), 840.0f + b,
                                5040.0f * (1.0f - 0.01f * b), 560.0f - b);
        float V; float4 o0, o1;
        battery_compute(s0, s1, 1.5f + 0.1f * b, q, 0.015f, 1.0f / 7.0e6f,
                        Wp1, bp1, Wp2, bp2, Wp3, bp3, Wn, bn, V, o0, o1);
        ws[idx] = V + o0.y + o1.w;                 // keep everything live, 4B write
    }
}

// ---- ablation C: memory-only (full reads + full-size writes, trivial compute) ----
__global__ __launch_bounds__(256) void ablate_memory_kernel(
    const float* __restrict__ inputs, const float* __restrict__ states,
    const float* __restrict__ qMax, const float* __restrict__ Ro,
    float* __restrict__ wsX,   // n*8 floats
    float* __restrict__ wsV)   // n floats
{
    const int t      = blockIdx.x * 256 + threadIdx.x;
    const int stride = gridDim.x * 256;
#pragma unroll
    for (int e = 0; e < ELEMS; ++e) {
        int idx = t + e * stride;
        float4 s0 = ((const float4*)states)[idx * 2 + 0];
        float4 s1 = ((const float4*)states)[idx * 2 + 1];
        float a = inputs[idx], b = qMax[idx], c = Ro[idx];
        float4 o0 = make_float4(s0.x + a, s0.y + b, s0.z + c, s0.w + a);
        float4 o1 = make_float4(s1.x + b, s1.y + c, s1.z + a, s1.w + b);
        ((float4*)wsX)[idx * 2 + 0] = o0;
        ((float4*)wsX)[idx * 2 + 1] = o1;
        wsV[idx] = a + b + c + s0.x + s1.x;
    }
}

extern "C" void kernel_launch(void* const* d_in, const int* in_sizes, int n_in,
                              void* d_out, int out_size, void* d_ws, size_t ws_size,
                              hipStream_t stream) {
    const float* inputs = (const float*)d_in[0];
    const float* states = (const float*)d_in[1];
    const float* qMax   = (const float*)d_in[2];
    const float* Ro     = (const float*)d_in[3];
    const float* tDiff  = (const float*)d_in[4];
    const float* Wp1    = (const float*)d_in[5];
    const float* bp1    = (const float*)d_in[6];
    const float* Wp2    = (const float*)d_in[7];
    const float* bp2    = (const float*)d_in[8];
    const float* Wp3    = (const float*)d_in[9];
    const float* bp3    = (const float*)d_in[10];
    const float* Wn     = (const float*)d_in[11];
    const float* bn     = (const float*)d_in[12];

    const int n = in_sizes[0];           // B
    float* outV = (float*)d_out;         // output 0: V, B floats
    float* outX = (float*)d_out + n;     // output 1: Xnew, B*8 floats

    const int threads = 256;
    const int chunk   = threads * ELEMS;

    if (n % chunk == 0) {
        const int blocks = n / chunk;
        battery_step_kernel<true><<<dim3(blocks), dim3(threads), 0, stream>>>(
            inputs, states, qMax, Ro, tDiff,
            Wp1, bp1, Wp2, bp2, Wp3, bp3, Wn, bn, outV, outX, n);

        // --- diagnostics (remove once bottleneck is identified) ---
        if (ws_size >= (size_t)n * sizeof(float)) {
            ablate_compute_kernel<<<dim3(blocks), dim3(threads), 0, stream>>>(
                qMax, Wp1, bp1, Wp2, bp2, Wp3, bp3, Wn, bn, (float*)d_ws);
        }
        if (ws_size >= (size_t)n * 9 * sizeof(float)) {
            ablate_memory_kernel<<<dim3(blocks), dim3(threads), 0, stream>>>(
                inputs, states, qMax, Ro,
                (float*)d_ws, (float*)d_ws + (size_t)n * 8);
        }
    } else {
        const int blocks = (n + chunk - 1) / chunk;
        battery_step_kernel<false><<<dim3(blocks), dim3(threads), 0, stream>>>(
            inputs, states, qMax, Ro, tDiff,
            Wp1, bp1, Wp2, bp2, Wp3, bp3, Wn, bn, outV, outX, n);
    }
}

// Round 9
// 198.919 us; speedup vs baseline: 1.1062x; 1.1062x over previous
//
#include <hip/hip_runtime.h>

#define DEVFN __device__ __forceinline__

typedef float f32x4 __attribute__((ext_vector_type(4)));

DEVFN float fast_rcp(float x)   { return __builtin_amdgcn_rcpf(x); }
DEVFN float fast_rsqrt(float x) { return __builtin_amdgcn_rsqf(x); }

DEVFN float fast_tanh(float x) {
    // tanh(x) = 1 - 2/(exp(2x)+1); stable at both tails.
    float e = __expf(2.0f * x);
    return 1.0f - 2.0f * fast_rcp(e + 1.0f);
}

DEVFN float fast_asinh(float z) {
    float az = fabsf(z);
    float r = __logf(az + sqrtf(fmaf(az, az, 1.0f)));
    return copysignf(r, z);
}

constexpr int ELEMS = 8;

// ---- per-element physics + MLP ----
DEVFN void battery_compute(
    f32x4 s0, f32x4 s1, float i, float qm, float ro, float invTD,
    const float* __restrict__ Wp1, const float* __restrict__ bp1,
    const float* __restrict__ Wp2, const float* __restrict__ bp2,
    const float* __restrict__ Wp3, const float* __restrict__ bp3,
    const float* __restrict__ Wn,  const float* __restrict__ bn,
    float& V, f32x4& o0, f32x4& o1)
{
    const float invVOLB = 1.0f / 1.98e-5f;
    const float invVOLS = 1.0f / 2.2e-6f;
    const float RTFA    = 8.3144621f / 96487.0f / 0.5f;  // R/F/alpha
    const float RF      = 8.3144621f / 96487.0f;         // R/F

    const float Tb = s0.x, Vo = s0.y, Vsn = s0.z, Vsp = s0.w;
    const float qnB = s1.x, qnS = s1.y, qpB = s1.z, qpS = s1.w;

    const float qSMax = qm * 1000.0f;
    const float rq    = fast_rcp(qSMax);

    float xpS = fminf(fmaxf(qpS * rq, 1e-18f), 1.0f);
    float xnS = fminf(fmaxf(qnS * rq, 1e-18f), 1.0f);

    // z = i*2500 / (1e-18 + 20000*sqrt(u))  ~=  i*0.125*rsqrt(u)
    float un = (1.0f - xnS) * xnS;
    float up = (1.0f - xpS) * xpS;
    float zn = i * 0.125f * fast_rsqrt(fmaxf(un, 1e-30f));
    float zp = i * 0.125f * fast_rsqrt(fmaxf(up, 1e-30f));

    float qdotn = (qnB * invVOLB - qnS * invVOLS) * invTD;
    float qdotp = (qpB * invVOLB - qpS * invVOLS) * invTD;

    float Vodot = (i * ro * 10.0f - Vo) * 0.1f;

    float VsnNom = RTFA * Tb * fast_asinh(zn);
    float VspNom = RTFA * Tb * fast_asinh(zp);

    const float X0 = Tb;
    const float X1 = Vo + Vodot;
    const float X2 = Vsn + (VsnNom - Vsn) * (1.0f / 90.0f);
    const float X3 = Vsp + (VspNom - Vsp) * (1.0f / 90.0f);
    const float X4 = qnB - qdotn;
    const float X5 = qnS + (qdotn - i);
    const float X6 = qpB - qdotp;
    const float X7 = qpS + (i + qdotp);

    const float xp2 = X7 * rq;
    const float xn2 = X5 * rq;

    // tiny MLP (weights live in scalar regs)
    float h1[8];
#pragma unroll
    for (int j = 0; j < 8; ++j)
        h1[j] = fast_tanh(fmaf(xp2, Wp1[j], bp1[j]));

    float h2[4];
#pragma unroll
    for (int k = 0; k < 4; ++k) {
        float acc = bp2[k];
#pragma unroll
        for (int j = 0; j < 8; ++j)
            acc = fmaf(h1[j], Wp2[j * 4 + k], acc);
        h2[k] = fast_tanh(acc);
    }

    float VepMLP = bp3[0];
#pragma unroll
    for (int k = 0; k < 4; ++k)
        VepMLP = fmaf(h2[k], Wp3[k], VepMLP);

    const float VenMLP = fmaf(xn2, Wn[0], bn[0]);

    // log(slp) - log(sln) = log( (1-xp2)*xn2 / (xp2*(1-xn2)) )
    float ratio = ((1.0f - xp2) * xn2) * fast_rcp(xp2 * (1.0f - xn2));
    float logr  = __logf(ratio);

    V = (4.03f - 0.01f) + RF * X0 * logr + VepMLP - VenMLP - X1 - X2 - X3;
    o0.x = X0; o0.y = X1; o0.z = X2; o0.w = X3;
    o1.x = X4; o1.y = X5; o1.z = X6; o1.w = X7;
}

template<bool EXACT>
__global__ __launch_bounds__(256, 4) void battery_step_kernel(
    const float* __restrict__ inputs, const float* __restrict__ states,
    const float* __restrict__ qMax, const float* __restrict__ Ro,
    const float* __restrict__ tDiff,
    const float* __restrict__ Wp1, const float* __restrict__ bp1,
    const float* __restrict__ Wp2, const float* __restrict__ bp2,
    const float* __restrict__ Wp3, const float* __restrict__ bp3,
    const float* __restrict__ Wn,  const float* __restrict__ bn,
    float* __restrict__ outV, float* __restrict__ outX, int n)
{
    const int t      = blockIdx.x * 256 + threadIdx.x;
    const int stride = gridDim.x * 256;

    const float invTD = fast_rcp(tDiff[0]);

    // ---- batch-load ALL elements first: ~40 outstanding loads per wave ----
    f32x4 s0[ELEMS], s1[ELEMS];
    float cur[ELEMS], qm[ELEMS], ro[ELEMS];
    bool  ok[ELEMS];
#pragma unroll
    for (int e = 0; e < ELEMS; ++e) {
        const int idx = t + e * stride;
        ok[e] = EXACT || (idx < n);
        if (ok[e]) {
            s0[e]  = ((const f32x4*)states)[idx * 2 + 0];
            s1[e]  = ((const f32x4*)states)[idx * 2 + 1];
            cur[e] = inputs[idx];
            qm[e]  = qMax[idx];
            ro[e]  = Ro[idx];
        }
    }

    // ---- compute + nontemporal stores ----
#pragma unroll
    for (int e = 0; e < ELEMS; ++e) {
        if (!ok[e]) continue;
        const int idx = t + e * stride;
        float V; f32x4 o0, o1;
        battery_compute(s0[e], s1[e], cur[e], qm[e], ro[e], invTD,
                        Wp1, bp1, Wp2, bp2, Wp3, bp3, Wn, bn,
                        V, o0, o1);
        __builtin_nontemporal_store(V, outV + idx);
        __builtin_nontemporal_store(o0, (f32x4*)outX + idx * 2 + 0);
        __builtin_nontemporal_store(o1, (f32x4*)outX + idx * 2 + 1);
    }
}

extern "C" void kernel_launch(void* const* d_in, const int* in_sizes, int n_in,
                              void* d_out, int out_size, void* d_ws, size_t ws_size,
                              hipStream_t stream) {
    const float* inputs = (const float*)d_in[0];
    const float* states = (const float*)d_in[1];
    const float* qMax   = (const float*)d_in[2];
    const float* Ro     = (const float*)d_in[3];
    const float* tDiff  = (const float*)d_in[4];
    const float* Wp1    = (const float*)d_in[5];
    const float* bp1    = (const float*)d_in[6];
    const float* Wp2    = (const float*)d_in[7];
    const float* bp2    = (const float*)d_in[8];
    const float* Wp3    = (const float*)d_in[9];
    const float* bp3    = (const float*)d_in[10];
    const float* Wn     = (const float*)d_in[11];
    const float* bn     = (const float*)d_in[12];

    const int n = in_sizes[0];           // B
    float* outV = (float*)d_out;         // output 0: V, B floats
    float* outX = (float*)d_out + n;     // output 1: Xnew, B*8 floats

    const int threads = 256;
    const int chunk   = threads * ELEMS;

    if (n % chunk == 0) {
        const int blocks = n / chunk;
        battery_step_kernel<true><<<dim3(blocks), dim3(threads), 0, stream>>>(
            inputs, states, qMax, Ro, tDiff,
            Wp1, bp1, Wp2, bp2, Wp3, bp3, Wn, bn, outV, outX, n);
    } else {
        const int blocks = (n + chunk - 1) / chunk;
        battery_step_kernel<false><<<dim3(blocks), dim3(threads), 0, stream>>>(
            inputs, states, qMax, Ro, tDiff,
            Wp1, bp1, Wp2, bp2, Wp3, bp3, Wn, bn, outV, outX, n);
    }
}